// Round 15
// baseline (156.349 us; speedup 1.0000x reference)
//
#include <hip/hip_runtime.h>

typedef _Float16 half8  __attribute__((ext_vector_type(8)));
typedef float    f32x4  __attribute__((ext_vector_type(4)));
typedef unsigned int u32;

#define QLEN  512
#define NS    64
#define LS    128
#define EDIM  256

// barrier that does NOT drain vmcnt
__device__ __forceinline__ void block_sync_lds() {
    asm volatile("s_waitcnt lgkmcnt(0)" ::: "memory");
    __builtin_amdgcn_s_barrier();
    asm volatile("" ::: "memory");
}

__device__ __forceinline__ half8 cvt8(f32x4 a, f32x4 b) {
    half8 h;
    h[0]=(_Float16)a[0]; h[1]=(_Float16)a[1]; h[2]=(_Float16)a[2]; h[3]=(_Float16)a[3];
    h[4]=(_Float16)b[0]; h[5]=(_Float16)b[1]; h[6]=(_Float16)b[2]; h[7]=(_Float16)b[3];
    return h;
}

// ---- K staging (proven layout): chunk = 32 l x 256 e fp16 -> quarter lt ----
#define KLOAD(dst, lt) do {                                                   \
  _Pragma("unroll") for (int it = 0; it < 4; ++it) {                          \
    int f = it * 2048 + tid * 8; int r = f >> 8; int e0 = f & 255;            \
    const float* src = kbase + (size_t)((lt) * 32 + r) * EDIM + e0;           \
    dst[2*it]   = *(const f32x4*)src;                                         \
    dst[2*it+1] = *(const f32x4*)(src + 4); } } while (0)

#define KSTORE(sv, lt) do {                                                   \
  _Pragma("unroll") for (int it = 0; it < 4; ++it) {                          \
    int f = it * 2048 + tid * 8; int r = f >> 8; int e0 = f & 255;            \
    half8 h = cvt8(sv[2*it], sv[2*it+1]);                                     \
    *(half8*)(kvbuf + (lt) * 16384 + r * 512 + ((e0 * 2) ^ ((r & 7) << 4))) = h; } } while (0)

// ---- V staging (R8-proven conflict-free layout): chunk p -> quarter p ----
// within quarter: e<128 at e*64, e>=128 at 8192+(e-128)*64; col swz (u^((vp>>1)&3))
#define VLOAD(dL, dH, lt) do {                                                \
  const float* vb0 = vbase + (size_t)((lt) * 32 + vlh * 16) * EDIM + vp;      \
  _Pragma("unroll") for (int i = 0; i < 16; ++i) {                            \
    dL[i] = vb0[(size_t)i * EDIM];                                            \
    dH[i] = vb0[(size_t)i * EDIM + 128]; } } while (0)

#define VSTORE(dL, dH, p) do {                                                \
  _Pragma("unroll") for (int jj = 0; jj < 2; ++jj) {                          \
    half8 h0, h1;                                                             \
    _Pragma("unroll") for (int j = 0; j < 8; ++j) {                           \
      h0[j] = (_Float16)dL[jj*8+j]; h1[j] = (_Float16)dH[jj*8+j]; }           \
    int u   = vlh * 2 + jj;                                                   \
    int a0  = (p) * 16384 + vp * 64 + ((u ^ ((vp >> 1) & 3)) * 16);           \
    *(half8*)(kvbuf + a0)        = h0;                                        \
    *(half8*)(kvbuf + a0 + 8192) = h1; } } while (0)

// ---- pack + exchange one tile's P^T -> pf[4] (proven network) ----
#define MAKE_PF(sacc, pf) do {                                                \
  u32 pk0[8], pk1[8];                                                         \
  _Pragma("unroll") for (int t = 0; t < 8; ++t) {                             \
    pk0[t] = __builtin_bit_cast(u32, __builtin_amdgcn_cvt_pkrtz(sacc[t][0], sacc[t][1])); \
    pk1[t] = __builtin_bit_cast(u32, __builtin_amdgcn_cvt_pkrtz(sacc[t][2], sacc[t][3])); \
  }                                                                           \
  _Pragma("unroll") for (int lt = 0; lt < 4; ++lt) {                          \
    u32 zx = sel2 ? pk0[2*lt+1] : pk0[2*lt];                                  \
    u32 zy = sel2 ? pk1[2*lt+1] : pk1[2*lt];                                  \
    u32 wx = sel2 ? pk0[2*lt]   : pk0[2*lt+1];                                \
    u32 wy = sel2 ? pk1[2*lt]   : pk1[2*lt+1];                                \
    u32 az0 = (u32)__shfl((int)zx, s0l, 64), az1 = (u32)__shfl((int)zy, s0l, 64); \
    u32 aw0 = (u32)__shfl((int)wx, s0l, 64), aw1 = (u32)__shfl((int)wy, s0l, 64); \
    u32 bz0 = (u32)__shfl((int)zx, s1l, 64), bz1 = (u32)__shfl((int)zy, s1l, 64); \
    u32 bw0 = (u32)__shfl((int)wx, s1l, 64), bw1 = (u32)__shfl((int)wy, s1l, 64); \
    union { u32 u[4]; half8 h; } t_;                                          \
    t_.u[0] = useZ ? az0 : aw0;  t_.u[1] = useZ ? az1 : aw1;                  \
    t_.u[2] = useZ ? bz0 : bw0;  t_.u[3] = useZ ? bz1 : bw1;                  \
    pf[lt] = t_.h; } } while (0)

// ---- PV dual-tile: one V frag read feeds both accumulators; quarter lt ----
#define PV2(lt) do {                                                          \
  const unsigned char* vb = kvbuf + (lt) * 16384;                             \
  _Pragma("unroll") for (int et = 0; et < 16; ++et) {                         \
    int e = et * 16 + c;                                                      \
    half8 vf = *(const half8*)(vb + (size_t)e * 64 + ((g ^ ((c >> 1) & 3)) * 16)); \
    oaccA[et] = __builtin_amdgcn_mfma_f32_16x16x32_f16(vf, pfA[lt], oaccA[et], 0, 0, 0); \
    oaccB[et] = __builtin_amdgcn_mfma_f32_16x16x32_f16(vf, pfB[lt], oaccB[et], 0, 0, 0); } \
  } while (0)

__global__ __launch_bounds__(256, 2)
void DotAttn_20083267076209_kernel(const float* __restrict__ qg,
                                   const float* __restrict__ kg,
                                   const float* __restrict__ vg,
                                   const int*   __restrict__ maskg,
                                   float*       __restrict__ outg)
{
    // 64 KB: full K [128][256] fp16, then V^T quarters (chunk p -> quarter p)
    __shared__ __align__(16) unsigned char kvbuf[65536];

    const int tid  = threadIdx.x;
    const int lane = tid & 63;
    const int c    = lane & 15;
    const int g    = lane >> 4;
    const int vp   = tid & 127;   // V e-column (also e+128)
    const int vlh  = tid >> 7;    // V l-half within a 32-l chunk
    const int w    = tid >> 6;

    const bool sel2 = (g >= 2);
    const bool useZ = (g == 0) || (g == 3);
    const int  s0l  = c + ((g & 1) << 5);
    const int  s1l  = s0l + 16;

    // grid 2048: 4 qt-sharers of (b,s) on one XCD (R13-proven)
    const int bid = blockIdx.x;
    const int xcd = bid & 7;
    const int qt  = (bid >> 3) & 3;           // 4 q-tiles of 128
    const int b   = (bid >> 5) & 7;
    const int s   = (bid >> 8) * 8 + xcd;

    const float* kbase  = kg + (size_t)(b * NS + s) * LS * EDIM;
    const float* vbase  = vg + (size_t)(b * NS + s) * LS * EDIM;
    const float* qbaseA = qg + ((size_t)b * QLEN + (size_t)qt * 128 + (size_t)w * 16) * EDIM;
    const float* qbaseB = qbaseA + (size_t)64 * EDIM;

    // mask loads first
    const int* mb = maskg + (b * NS + s) * LS;
    int mraw0 = mb[lane];
    int mraw1 = mb[64 + lane];

    // ---- stage ALL of K before one barrier (2 alternating reg sets) ----
    f32x4 kr0[8], kr1[8];
    KLOAD(kr0, 0);
    KLOAD(kr1, 1);

    // Q frags for both tiles (loads overlap K staging)
    half8 qfA[8], qfB[8];
#pragma unroll
    for (int ks = 0; ks < 8; ++ks) {
        const float* pA = qbaseA + (size_t)c * EDIM + ks * 32 + g * 8;
        const float* pB = qbaseB + (size_t)c * EDIM + ks * 32 + g * 8;
        qfA[ks] = cvt8(*(const f32x4*)pA, *(const f32x4*)(pA + 4));
        qfB[ks] = cvt8(*(const f32x4*)pB, *(const f32x4*)(pB + 4));
    }

    unsigned long long m0 = __ballot(mraw0 != 0);
    unsigned long long m1 = __ballot(mraw1 != 0);

    KSTORE(kr0, 0);
    KLOAD(kr0, 2);
    KSTORE(kr1, 1);
    KLOAD(kr1, 3);
    KSTORE(kr0, 2);
    KSTORE(kr1, 3);

    block_sync_lds();     // #1: K fully staged

    // ---- S^T = K Q^T, both tiles: ONE uninterrupted ds_read+MFMA stream ----
    f32x4 saccA[8], saccB[8];
#pragma unroll
    for (int t = 0; t < 8; ++t) {
        saccA[t] = (f32x4){0.f, 0.f, 0.f, 0.f};
        saccB[t] = (f32x4){0.f, 0.f, 0.f, 0.f};
    }

    float vr0L[16], vr0H[16], vr1L[16], vr1H[16];

#pragma unroll
    for (int lt = 0; lt < 4; ++lt) {
        const unsigned char* kb = kvbuf + lt * 16384;
#pragma unroll
        for (int lb = 0; lb < 2; ++lb) {
            int row  = lb * 16 + c;
            int base = row * 512;
            int sw   = (c & 7) << 4;
#pragma unroll
            for (int ks = 0; ks < 8; ++ks) {
                half8 kf = *(const half8*)(kb + base + ((ks * 64 + g * 16) ^ sw));
                saccA[lt * 2 + lb] =
                    __builtin_amdgcn_mfma_f32_16x16x32_f16(kf, qfA[ks], saccA[lt * 2 + lb], 0, 0, 0);
                saccB[lt * 2 + lb] =
                    __builtin_amdgcn_mfma_f32_16x16x32_f16(kf, qfB[ks], saccB[lt * 2 + lb], 0, 0, 0);
            }
        }
        if (lt == 2) { VLOAD(vr0L, vr0H, 0); }   // V chunks 0,1 in flight under S tail
        if (lt == 3) { VLOAD(vr1L, vr1H, 1); }
    }

    // ---- mask both tiles ----
#pragma unroll
    for (int t = 0; t < 8; ++t) {
        unsigned bits = (unsigned)(((t < 4 ? m0 : m1) >> ((t & 3) * 16 + 4 * g)) & 0xFull);
#pragma unroll
        for (int r = 0; r < 4; ++r)
            if (!((bits >> r) & 1)) { saccA[t][r] = -1e30f; saccB[t][r] = -1e30f; }
    }

    // ---- softmax per tile ----
#pragma unroll
    for (int tile = 0; tile < 2; ++tile) {
        f32x4* sc = tile ? saccB : saccA;
        float m = sc[0][0];
#pragma unroll
        for (int t = 0; t < 8; ++t)
#pragma unroll
            for (int r = 0; r < 4; ++r) m = fmaxf(m, sc[t][r]);
        m = fmaxf(m, __shfl_xor(m, 16, 64));
        m = fmaxf(m, __shfl_xor(m, 32, 64));
        float sum = 0.f;
#pragma unroll
        for (int t = 0; t < 8; ++t)
#pragma unroll
            for (int r = 0; r < 4; ++r) {
                float p = __expf(sc[t][r] - m);
                sc[t][r] = p;
                sum += p;
            }
        sum += __shfl_xor(sum, 16, 64);
        sum += __shfl_xor(sum, 32, 64);
        float inv = 1.f / sum;
#pragma unroll
        for (int t = 0; t < 8; ++t)
#pragma unroll
            for (int r = 0; r < 4; ++r) sc[t][r] *= inv;
    }

    // ---- pack + exchange both tiles (sacc dies here) ----
    half8 pfA[4], pfB[4];
    MAKE_PF(saccA, pfA);
    MAKE_PF(saccB, pfB);

    // ---- O^T = V^T P^T : V reuses K's 64 KB, 2 staging phases, 3 more barriers ----
    f32x4 oaccA[16], oaccB[16];
#pragma unroll
    for (int et = 0; et < 16; ++et) {
        oaccA[et] = (f32x4){0.f, 0.f, 0.f, 0.f};
        oaccB[et] = (f32x4){0.f, 0.f, 0.f, 0.f};
    }

    block_sync_lds();         // #2: all waves done S reads — K dead everywhere
    VSTORE(vr0L, vr0H, 0);    // quarter 0
    VSTORE(vr1L, vr1H, 1);    // quarter 1
    VLOAD(vr0L, vr0H, 2);     // chunks 2,3 in flight
    VLOAD(vr1L, vr1H, 3);
    block_sync_lds();         // #3: quarters 0,1 visible
    PV2(0);                   // reads quarter 0
    PV2(1);                   // reads quarter 1
    VSTORE(vr0L, vr0H, 2);    // quarter 2 — disjoint from PV reads; loads arrived under PV
    VSTORE(vr1L, vr1H, 3);    // quarter 3
    block_sync_lds();         // #4: quarters 2,3 visible; all done PV2(0,1)
    PV2(2);
    PV2(3);

    // ---- epilogue: q = qt*128 + {0,64} + w*16 + c, e = et*16 + 4g + r ----
    float* obA = outg + (((size_t)b * QLEN + (size_t)qt * 128 + w * 16 + c) * NS + s) * EDIM + 4 * g;
    float* obB = obA + (size_t)64 * NS * EDIM;
#pragma unroll
    for (int et = 0; et < 16; ++et) {
        *(f32x4*)(obA + et * 16) = oaccA[et];
        *(f32x4*)(obB + et * 16) = oaccB[et];
    }
}

extern "C" void kernel_launch(void* const* d_in, const int* in_sizes, int n_in,
                              void* d_out, int out_size, void* d_ws, size_t ws_size,
                              hipStream_t stream) {
    const float* q    = (const float*)d_in[0];
    const float* k    = (const float*)d_in[1];
    const float* v    = (const float*)d_in[2];
    const int*   mask = (const int*)d_in[3];
    float* out = (float*)d_out;
    dim3 grid(2048);   // 8 xcd * 4 qt * 8 b * 8 s-high
    dim3 block(256);
    hipLaunchKernelGGL(DotAttn_20083267076209_kernel, grid, block, 0, stream,
                       q, k, v, mask, out);
}

// Round 16
// 141.090 us; speedup vs baseline: 1.1081x; 1.1081x over previous
//
#include <hip/hip_runtime.h>

typedef _Float16 half8  __attribute__((ext_vector_type(8)));
typedef float    f32x4  __attribute__((ext_vector_type(4)));
typedef unsigned int u32;

#define QLEN  512
#define NS    64
#define LS    128
#define EDIM  256

// barrier that does NOT drain vmcnt
__device__ __forceinline__ void block_sync_lds() {
    asm volatile("s_waitcnt lgkmcnt(0)" ::: "memory");
    __builtin_amdgcn_s_barrier();
    asm volatile("" ::: "memory");
}

__device__ __forceinline__ half8 cvt8(f32x4 a, f32x4 b) {
    half8 h;
    h[0]=(_Float16)a[0]; h[1]=(_Float16)a[1]; h[2]=(_Float16)a[2]; h[3]=(_Float16)a[3];
    h[4]=(_Float16)b[0]; h[5]=(_Float16)b[1]; h[6]=(_Float16)b[2]; h[7]=(_Float16)b[3];
    return h;
}

// ---- K staging (proven layout): chunk = 32 l x 256 e fp16 (16 KB), half lt&1 ----
#define KLOAD(lt) do {                                                        \
  _Pragma("unroll") for (int it = 0; it < 4; ++it) {                          \
    int f = it * 2048 + tid * 8; int r = f >> 8; int e0 = f & 255;            \
    const float* src = kbase + (size_t)((lt) * 32 + r) * EDIM + e0;           \
    kr[2*it]   = *(const f32x4*)src;                                          \
    kr[2*it+1] = *(const f32x4*)(src + 4); } } while (0)

#define KSTORE(bi) do {                                                       \
  _Pragma("unroll") for (int it = 0; it < 4; ++it) {                          \
    int f = it * 2048 + tid * 8; int r = f >> 8; int e0 = f & 255;            \
    half8 h = cvt8(kr[2*it], kr[2*it+1]);                                     \
    *(half8*)(kvbuf + (bi) * 16384 + r * 512 + ((e0 * 2) ^ ((r & 7) << 4))) = h; } } while (0)

// ---- V staging (proven conflict-free layout): chunk p -> half (p&1) ----
#define VLOAD(lt) do {                                                        \
  const float* vb0 = vbase + (size_t)((lt) * 32 + vlh * 16) * EDIM + vp;      \
  _Pragma("unroll") for (int i = 0; i < 16; ++i) {                            \
    vrL[i] = vb0[(size_t)i * EDIM];                                           \
    vrH[i] = vb0[(size_t)i * EDIM + 128]; } } while (0)

#define VSTORE(p) do {                                                        \
  _Pragma("unroll") for (int jj = 0; jj < 2; ++jj) {                          \
    half8 h0, h1;                                                             \
    _Pragma("unroll") for (int j = 0; j < 8; ++j) {                           \
      h0[j] = (_Float16)vrL[jj*8+j]; h1[j] = (_Float16)vrH[jj*8+j]; }         \
    int u   = vlh * 2 + jj;                                                   \
    int a0  = ((p) & 1) * 16384 + vp * 64 + ((u ^ ((vp >> 1) & 3)) * 16);     \
    *(half8*)(kvbuf + a0)        = h0;                                        \
    *(half8*)(kvbuf + a0 + 8192) = h1; } } while (0)

// ---- pack + exchange one tile's P^T -> pf[4] (proven network) ----
#define MAKE_PF(sacc, pf) do {                                                \
  u32 pk0[8], pk1[8];                                                         \
  _Pragma("unroll") for (int t = 0; t < 8; ++t) {                             \
    pk0[t] = __builtin_bit_cast(u32, __builtin_amdgcn_cvt_pkrtz(sacc[t][0], sacc[t][1])); \
    pk1[t] = __builtin_bit_cast(u32, __builtin_amdgcn_cvt_pkrtz(sacc[t][2], sacc[t][3])); \
  }                                                                           \
  _Pragma("unroll") for (int lt = 0; lt < 4; ++lt) {                          \
    u32 zx = sel2 ? pk0[2*lt+1] : pk0[2*lt];                                  \
    u32 zy = sel2 ? pk1[2*lt+1] : pk1[2*lt];                                  \
    u32 wx = sel2 ? pk0[2*lt]   : pk0[2*lt+1];                                \
    u32 wy = sel2 ? pk1[2*lt]   : pk1[2*lt+1];                                \
    u32 az0 = (u32)__shfl((int)zx, s0l, 64), az1 = (u32)__shfl((int)zy, s0l, 64); \
    u32 aw0 = (u32)__shfl((int)wx, s0l, 64), aw1 = (u32)__shfl((int)wy, s0l, 64); \
    u32 bz0 = (u32)__shfl((int)zx, s1l, 64), bz1 = (u32)__shfl((int)zy, s1l, 64); \
    u32 bw0 = (u32)__shfl((int)wx, s1l, 64), bw1 = (u32)__shfl((int)wy, s1l, 64); \
    union { u32 u[4]; half8 h; } t_;                                          \
    t_.u[0] = useZ ? az0 : aw0;  t_.u[1] = useZ ? az1 : aw1;                  \
    t_.u[2] = useZ ? bz0 : bw0;  t_.u[3] = useZ ? bz1 : bw1;                  \
    pf[lt] = t_.h; } } while (0)

// ---- PV dual-tile: one V frag read feeds both accumulators ----
#define PV2(lt) do {                                                          \
  const unsigned char* vb = kvbuf + ((lt) & 1) * 16384;                       \
  _Pragma("unroll") for (int et = 0; et < 16; ++et) {                         \
    int e = et * 16 + c;                                                      \
    half8 vf = *(const half8*)(vb + (size_t)e * 64 + ((g ^ ((c >> 1) & 3)) * 16)); \
    oaccA[et] = __builtin_amdgcn_mfma_f32_16x16x32_f16(vf, pfA[lt], oaccA[et], 0, 0, 0); \
    oaccB[et] = __builtin_amdgcn_mfma_f32_16x16x32_f16(vf, pfB[lt], oaccB[et], 0, 0, 0); } \
  } while (0)

__global__ __launch_bounds__(256, 2)
void DotAttn_20083267076209_kernel(const float* __restrict__ qg,
                                   const float* __restrict__ kg,
                                   const float* __restrict__ vg,
                                   const int*   __restrict__ maskg,
                                   float*       __restrict__ outg)
{
    // union: K double-buffer 2x16KB  /  V chunk halves 2x16KB (chunk p -> half p&1)
    __shared__ __align__(16) unsigned char kvbuf[32768];

    const int tid  = threadIdx.x;
    const int lane = tid & 63;
    const int c    = lane & 15;
    const int g    = lane >> 4;
    const int vp   = tid & 127;   // V e-column (also e+128)
    const int vlh  = tid >> 7;    // V l-half within a 32-l chunk
    const int w    = tid >> 6;

    const bool sel2 = (g >= 2);
    const bool useZ = (g == 0) || (g == 3);
    const int  s0l  = c + ((g & 1) << 5);
    const int  s1l  = s0l + 16;

    // grid 2048: 4 qt-sharers of (b,s) on one XCD
    const int bid = blockIdx.x;
    const int xcd = bid & 7;
    const int qt  = (bid >> 3) & 3;           // 4 q-tiles of 128
    const int b   = (bid >> 5) & 7;
    const int s   = (bid >> 8) * 8 + xcd;

    const float* kbase  = kg + (size_t)(b * NS + s) * LS * EDIM;
    const float* vbase  = vg + (size_t)(b * NS + s) * LS * EDIM;
    const float* qbaseA = qg + ((size_t)b * QLEN + (size_t)qt * 128 + (size_t)w * 16) * EDIM;
    const float* qbaseB = qbaseA + (size_t)64 * EDIM;

    // mask loads first
    const int* mb = maskg + (b * NS + s) * LS;
    int mraw0 = mb[lane];
    int mraw1 = mb[64 + lane];

    f32x4 kr[8];
    KLOAD(0);

    // Q frags for both tiles: lane (c,g) holds Q[q][e = ks*32 + g*8 + j]
    half8 qfA[8], qfB[8];
#pragma unroll
    for (int ks = 0; ks < 8; ++ks) {
        const float* pA = qbaseA + (size_t)c * EDIM + ks * 32 + g * 8;
        const float* pB = qbaseB + (size_t)c * EDIM + ks * 32 + g * 8;
        qfA[ks] = cvt8(*(const f32x4*)pA, *(const f32x4*)(pA + 4));
        qfB[ks] = cvt8(*(const f32x4*)pB, *(const f32x4*)(pB + 4));
    }

    unsigned long long m0 = __ballot(mraw0 != 0);
    unsigned long long m1 = __ballot(mraw1 != 0);

    float vrL[16], vrH[16];

    // ---- S^T = K Q^T for both tiles: sacc*[t][r] = S^T[l = t*16+4g+r][q = c] ----
    f32x4 saccA[8], saccB[8];
#pragma unroll
    for (int t = 0; t < 8; ++t) {
        saccA[t] = (f32x4){0.f, 0.f, 0.f, 0.f};
        saccB[t] = (f32x4){0.f, 0.f, 0.f, 0.f};
    }

#pragma unroll
    for (int lt = 0; lt < 4; ++lt) {
        KSTORE(lt & 1);
        if (lt < 3) KLOAD(lt + 1);
        else        VLOAD(0);                 // V chunk0 in flight across barrier
        block_sync_lds();
        const unsigned char* kb = kvbuf + (lt & 1) * 16384;
#pragma unroll
        for (int lb = 0; lb < 2; ++lb) {
            int row  = lb * 16 + c;
            int base = row * 512;
            int sw   = (c & 7) << 4;
#pragma unroll
            for (int ks = 0; ks < 8; ++ks) {
                half8 kf = *(const half8*)(kb + base + ((ks * 64 + g * 16) ^ sw));
                saccA[lt * 2 + lb] =
                    __builtin_amdgcn_mfma_f32_16x16x32_f16(kf, qfA[ks], saccA[lt * 2 + lb], 0, 0, 0);
                saccB[lt * 2 + lb] =
                    __builtin_amdgcn_mfma_f32_16x16x32_f16(kf, qfB[ks], saccB[lt * 2 + lb], 0, 0, 0);
            }
        }
    }

    // ---- mask both tiles (per-lane l = t*16 + 4g + r) ----
#pragma unroll
    for (int t = 0; t < 8; ++t) {
        unsigned bits = (unsigned)(((t < 4 ? m0 : m1) >> ((t & 3) * 16 + 4 * g)) & 0xFull);
#pragma unroll
        for (int r = 0; r < 4; ++r)
            if (!((bits >> r) & 1)) { saccA[t][r] = -1e30f; saccB[t][r] = -1e30f; }
    }

    // ---- softmax over l, per tile ----
#pragma unroll
    for (int tile = 0; tile < 2; ++tile) {
        f32x4* sc = tile ? saccB : saccA;
        float m = sc[0][0];
#pragma unroll
        for (int t = 0; t < 8; ++t)
#pragma unroll
            for (int r = 0; r < 4; ++r) m = fmaxf(m, sc[t][r]);
        m = fmaxf(m, __shfl_xor(m, 16, 64));
        m = fmaxf(m, __shfl_xor(m, 32, 64));
        float sum = 0.f;
#pragma unroll
        for (int t = 0; t < 8; ++t)
#pragma unroll
            for (int r = 0; r < 4; ++r) {
                float p = __expf(sc[t][r] - m);
                sc[t][r] = p;
                sum += p;
            }
        sum += __shfl_xor(sum, 16, 64);
        sum += __shfl_xor(sum, 32, 64);
        float inv = 1.f / sum;
#pragma unroll
        for (int t = 0; t < 8; ++t)
#pragma unroll
            for (int r = 0; r < 4; ++r) sc[t][r] *= inv;
    }

    // ---- pack + exchange both tiles (sacc freed after this) ----
    half8 pfA[4], pfB[4];
    MAKE_PF(saccA, pfA);
    MAKE_PF(saccB, pfB);

    // ---- O^T = V^T P^T, dual accumulators, alternating 16-KB halves ----
    f32x4 oaccA[16], oaccB[16];
#pragma unroll
    for (int et = 0; et < 16; ++et) {
        oaccA[et] = (f32x4){0.f, 0.f, 0.f, 0.f};
        oaccB[et] = (f32x4){0.f, 0.f, 0.f, 0.f};
    }

    VSTORE(0);            // half0: all waves past lt3-barrier done reading half0
    VLOAD(1);
    block_sync_lds();     // a: chunk0 visible; all done K MFMA(3) (half1 free)
    PV2(0);               // reads half0
    VSTORE(1);            // half1 — disjoint from PV2(0)
    VLOAD(2);
    block_sync_lds();     // b: chunk1 visible; all done PV2(0)
    PV2(1);               // reads half1
    VSTORE(2);            // half0 — all past bar b
    VLOAD(3);
    block_sync_lds();     // c: chunk2 visible; all done PV2(1)
    PV2(2);               // reads half0
    VSTORE(3);            // half1 — disjoint from PV2(2)
    block_sync_lds();     // d: chunk3 visible; all done PV2(2)
    PV2(3);               // reads half1

    // ---- epilogue: q = qt*128 + {0,64} + w*16 + c, e = et*16 + 4g + r ----
    float* obA = outg + (((size_t)b * QLEN + (size_t)qt * 128 + w * 16 + c) * NS + s) * EDIM + 4 * g;
    float* obB = obA + (size_t)64 * NS * EDIM;
#pragma unroll
    for (int et = 0; et < 16; ++et) {
        *(f32x4*)(obA + et * 16) = oaccA[et];
        *(f32x4*)(obB + et * 16) = oaccB[et];
    }
}

extern "C" void kernel_launch(void* const* d_in, const int* in_sizes, int n_in,
                              void* d_out, int out_size, void* d_ws, size_t ws_size,
                              hipStream_t stream) {
    const float* q    = (const float*)d_in[0];
    const float* k    = (const float*)d_in[1];
    const float* v    = (const float*)d_in[2];
    const int*   mask = (const int*)d_in[3];
    float* out = (float*)d_out;
    dim3 grid(2048);   // 8 xcd * 4 qt * 8 b * 8 s-high
    dim3 block(256);
    hipLaunchKernelGGL(DotAttn_20083267076209_kernel, grid, block, 0, stream,
                       q, k, v, mask, out);
}